// Round 9
// baseline (314.241 us; speedup 1.0000x reference)
//
#include <hip/hip_runtime.h>
#include <hip/hip_cooperative_groups.h>
#include <hip/hip_bf16.h>

namespace cg = cooperative_groups;

typedef __attribute__((ext_vector_type(8))) unsigned short u16x8;
typedef __attribute__((ext_vector_type(4))) unsigned short u16x4;
typedef __attribute__((ext_vector_type(8))) short short8;
typedef __attribute__((ext_vector_type(4))) float floatx4;

#define BS 64
#define CIN 256
#define II 1024
#define OO 320
#define JJ 10
#define DD 32

__device__ __forceinline__ float b2f(unsigned short u) {
    union { unsigned int i; float f; } x; x.i = ((unsigned int)u) << 16; return x.f;
}
__device__ __forceinline__ unsigned short f2b(float f) {
    union { float f; unsigned int i; } x; x.f = f;
    unsigned int r = x.i + 0x7fffu + ((x.i >> 16) & 1u);
    return (unsigned short)(r >> 16);
}
// sum over the 16 lm-lanes (i dimension within a frag)
__device__ __forceinline__ float redlm(float v) {
    v += __shfl_xor(v, 1); v += __shfl_xor(v, 2);
    v += __shfl_xor(v, 4); v += __shfl_xor(v, 8);
    return v;
}
// full wave reduction
__device__ __forceinline__ float redwave(float v) {
    v += __shfl_xor(v, 1);  v += __shfl_xor(v, 2);  v += __shfl_xor(v, 4);
    v += __shfl_xor(v, 8);  v += __shfl_xor(v, 16); v += __shfl_xor(v, 32);
    return v;
}

// ---------- prep: W f32 [320][256] -> chunk-major frag-linear bf16 Wl ----------
// gid = (((oc*8 + ks)*4 + mtl)*4 + quad)*16 + lm ; group holds 8 bf16:
//   W[o = oc*64 + mtl*16 + lm][c = ks*32 + quad*8 + j], j=0..7
__global__ __launch_bounds__(256) void k_prepW(const float* __restrict__ W,
                                               unsigned short* __restrict__ Wl) {
    int gid = blockIdx.x * 256 + threadIdx.x;   // 40 blocks -> 10240
    int lm = gid & 15;
    int quad = (gid >> 4) & 3;
    int mtl = (gid >> 6) & 3;
    int ks = (gid >> 8) & 7;
    int oc = gid >> 11;
    const float* src = W + (size_t)(oc * 64 + mtl * 16 + lm) * CIN + ks * 32 + quad * 8;
    float4 v0 = *(const float4*)src;
    float4 v1 = *(const float4*)(src + 4);
    u16x8 u;
    u[0] = f2b(v0.x); u[1] = f2b(v0.y); u[2] = f2b(v0.z); u[3] = f2b(v0.w);
    u[4] = f2b(v1.x); u[5] = f2b(v1.y); u[6] = f2b(v1.z); u[7] = f2b(v1.w);
    *(u16x8*)(Wl + (size_t)gid * 8) = u;
}

// ---------- K1: GEMM (direct-from-x B-frags) + fused rowsum partials (R6 verbatim) ----------
__global__ __launch_bounds__(512) void k_gemm3(const float* __restrict__ x,
                                               const unsigned short* __restrict__ Wl,
                                               const float* __restrict__ Wb,
                                               unsigned short* __restrict__ pred,
                                               float* __restrict__ psum0) {
    __shared__ unsigned short AsF[2048 * 8];   // 32 KB: one o-chunk frag-linear
    __shared__ float ws_lds[8][OO];
    __shared__ float Wb_lds[OO];

    const int ic = blockIdx.x, b = blockIdx.y;
    const int t = threadIdx.x, w = t >> 6, l = t & 63;
    const int lm = l & 15, quad = l >> 4;

    if (t < OO) Wb_lds[t] = Wb[t];

    const float* xb = x + (size_t)b * CIN * II + ic * 128 + w * 16 + lm;
    short8 bfrag[8];
#pragma unroll
    for (int ks = 0; ks < 8; ++ks) {
        float tmp[8];
#pragma unroll
        for (int j = 0; j < 8; ++j) tmp[j] = xb[(size_t)(ks * 32 + quad * 8 + j) * II];
        short8 f;
#pragma unroll
        for (int j = 0; j < 8; ++j) f[j] = (short)f2b(tmp[j]);
        bfrag[ks] = f;
    }

    const int ibase = ic * 128 + w * 16 + lm;
#pragma unroll 1
    for (int oc = 0; oc < 5; ++oc) {
        __syncthreads();
        {
            const u16x8* src = (const u16x8*)Wl + oc * 2048;
            u16x8* dst = (u16x8*)AsF;
            for (int u = t; u < 2048; u += 512) dst[u] = src[u];
        }
        __syncthreads();

        floatx4 acc[4] = {};
#pragma unroll
        for (int ks = 0; ks < 8; ++ks)
#pragma unroll
            for (int mtl = 0; mtl < 4; ++mtl) {
                short8 af = *(const short8*)(AsF + (size_t)(((ks * 4 + mtl) * 4 + quad) * 16 + lm) * 8);
                acc[mtl] = __builtin_amdgcn_mfma_f32_16x16x32_bf16(af, bfrag[ks], acc[mtl], 0, 0, 0);
            }

#pragma unroll
        for (int mtl = 0; mtl < 4; ++mtl)
#pragma unroll
            for (int r = 0; r < 4; ++r) {
                int o = oc * 64 + mtl * 16 + quad * 4 + r;
                float v = acc[mtl][r] + Wb_lds[o];
                pred[((size_t)b * OO + o) * II + ibase] = f2b(v);
                float rs = redlm(v);
                if (lm == 0) ws_lds[w][o] = rs;
            }
    }
    __syncthreads();
    for (int u = t; u < OO; u += 512) {
        float s = 0.f;
#pragma unroll
        for (int ww = 0; ww < 8; ++ww) s += ws_lds[ww][u];
        psum0[((size_t)ic * BS + b) * OO + u] = s;
    }
}

// ---------- K2: all routing, cooperative, pred register-resident ----------
// grid (4 ic, 64 b) = 256 blocks (R5-proven co-residency: 1 block/CU) x 640 thr
// (10 waves; wave w = capsule j). Lane l holds pred[b][32w..32w+32][ic*256+4l .. +3]
// as 32 u16x4 loads (8B/lane, 512B/wave-instr), loaded ONCE, reused by both passes.
__global__ __launch_bounds__(640, 3) void k_route_all3(const float* __restrict__ psum0,
                                                       const unsigned short* __restrict__ pred,
                                                       float* __restrict__ psum1,
                                                       float* __restrict__ psum2,
                                                       float* __restrict__ out) {
    __shared__ float s_lds[OO];
    __shared__ float v_lds[OO];
    __shared__ float cf[JJ];
    __shared__ float dbuf[JJ][256];

    const int ic = blockIdx.x, b = blockIdx.y;
    const int t = threadIdx.x, w = t >> 6, l = t & 63;
    cg::grid_group grid = cg::this_grid();

    // ---- load this wave's pred rows once ----
    u16x4 vals[DD];
    {
        const unsigned short* pb = pred + ((size_t)b * OO + w * DD) * II + ic * 256 + 4 * l;
#pragma unroll
        for (int d = 0; d < DD; ++d)
            vals[d] = *(const u16x4*)(pb + (size_t)d * II);
    }

    // ---- s1 = 0.1 * sum of psum0 slices (gemm3 wrote 8 slices) ----
    if (t < OO) {
        float s = 0.f;
#pragma unroll
        for (int sl = 0; sl < 8; ++sl) s += psum0[((size_t)sl * BS + b) * OO + t];
        s_lds[t] = 0.1f * s;
    }
    __syncthreads();

    float dl0 = 0.f, dl1 = 0.f, dl2 = 0.f, dl3 = 0.f;  // pass-0 delta (replaces blog)

#pragma unroll 1
    for (int pass = 0; pass < 2; ++pass) {
        // squash s -> v
        if (t < JJ) {
            float n2 = 0.f;
#pragma unroll
            for (int d = 0; d < DD; ++d) { float v = s_lds[t * DD + d]; n2 += v * v; }
            cf[t] = sqrtf(n2) / (1.0f + n2);
        }
        __syncthreads();
        if (t < OO) v_lds[t] = s_lds[t] * cf[t >> 5];
        __syncthreads();

        // delta for j=w at lane's four i-columns
        float d0 = 0.f, d1 = 0.f, d2 = 0.f, d3 = 0.f;
#pragma unroll
        for (int d = 0; d < DD; ++d) {
            float vv = v_lds[w * DD + d];
            d0 += vv * b2f(vals[d][0]);
            d1 += vv * b2f(vals[d][1]);
            d2 += vv * b2f(vals[d][2]);
            d3 += vv * b2f(vals[d][3]);
        }
        float lg0, lg1, lg2, lg3;
        if (pass == 0) {
            dl0 = d0; dl1 = d1; dl2 = d2; dl3 = d3;
            lg0 = d0; lg1 = d1; lg2 = d2; lg3 = d3;
        } else {
            lg0 = dl0 + d0; lg1 = dl1 + d1; lg2 = dl2 + d2; lg3 = dl3 + d3;
        }
        dbuf[w][4 * l]     = lg0;
        dbuf[w][4 * l + 1] = lg1;
        dbuf[w][4 * l + 2] = lg2;
        dbuf[w][4 * l + 3] = lg3;
        __syncthreads();

        // softmax over j at each i (threads 0..255)
        if (t < 256) {
            float lg[JJ];
#pragma unroll
            for (int j = 0; j < JJ; ++j) lg[j] = dbuf[j][t];
            float m = lg[0];
#pragma unroll
            for (int j = 1; j < JJ; ++j) m = fmaxf(m, lg[j]);
            float Z = 0.f, c[JJ];
#pragma unroll
            for (int j = 0; j < JJ; ++j) { c[j] = __expf(lg[j] - m); Z += c[j]; }
            float inv = 1.0f / Z;
#pragma unroll
            for (int j = 0; j < JJ; ++j) dbuf[j][t] = c[j] * inv;
        }
        __syncthreads();

        // wsum partial for this ic slice: out rows o = w*32+d
        float c0 = dbuf[w][4 * l], c1 = dbuf[w][4 * l + 1];
        float c2 = dbuf[w][4 * l + 2], c3 = dbuf[w][4 * l + 3];
        float* pout = (pass == 0) ? psum1 : psum2;
#pragma unroll
        for (int d = 0; d < DD; ++d) {
            float p = c0 * b2f(vals[d][0]) + c1 * b2f(vals[d][1])
                    + c2 * b2f(vals[d][2]) + c3 * b2f(vals[d][3]);
            p = redwave(p);
            if (l == 0) pout[((size_t)ic * BS + b) * OO + w * DD + d] = p;
        }
        __syncthreads();
        __threadfence();
        grid.sync();

        // consume partials (4 slices) -> s_lds for next pass / final
        if (t < OO) {
            float s = 0.f;
#pragma unroll
            for (int sl = 0; sl < 4; ++sl) s += pout[((size_t)sl * BS + b) * OO + t];
            s_lds[t] = s;
        }
        __syncthreads();
    }

    // ---- final squash -> out (ic==0 blocks; s_lds holds s3) ----
    if (ic == 0) {
        if (t < JJ) {
            float n2 = 0.f;
#pragma unroll
            for (int d = 0; d < DD; ++d) { float v = s_lds[t * DD + d]; n2 += v * v; }
            cf[t] = sqrtf(n2) / (1.0f + n2);
        }
        __syncthreads();
        if (t < OO) out[(size_t)b * OO + t] = s_lds[t] * cf[t >> 5];
    }
}

extern "C" void kernel_launch(void* const* d_in, const int* in_sizes, int n_in,
                              void* d_out, int out_size, void* d_ws, size_t ws_size,
                              hipStream_t stream) {
    const float* x  = (const float*)d_in[0];  // [64][256][1024] f32
    const float* W  = (const float*)d_in[1];  // [320][256] f32
    const float* Wb = (const float*)d_in[2];  // [320] f32

    char* ws = (char*)d_ws;
    unsigned short* pred = (unsigned short*)ws;              // 41,943,040 B
    unsigned short* Wl   = (unsigned short*)(ws + 41943040); // 163,840 B  -> 42,106,880
    float* psum0 = (float*)(ws + 42106880);                  // 655,360 B  -> 42,762,240
    float* psum1 = (float*)(ws + 42762240);                  // 327,680 B  -> 43,089,920
    float* psum2 = (float*)(ws + 43089920);                  // 327,680 B  -> 43,417,600
    float* out   = (float*)d_out;

    k_prepW<<<40, 256, 0, stream>>>(W, Wl);
    k_gemm3<<<dim3(8, BS), 512, 0, stream>>>(x, Wl, Wb, pred, psum0);

    void* args[] = { (void*)&psum0, (void*)&pred, (void*)&psum1, (void*)&psum2, (void*)&out };
    (void)hipLaunchCooperativeKernel((void*)k_route_all3, dim3(4, BS), dim3(640),
                                     args, 0, stream);
}